// Round 3
// baseline (660.657 us; speedup 1.0000x reference)
//
#include <hip/hip_runtime.h>
#include <cstdint>
#include <cstddef>

#define B_   8
#define N_   8192
#define S_   2048
#define D1_  256
#define D2_  256
#define CIN_ 512

typedef __bf16 bf16x8 __attribute__((ext_vector_type(8)));
typedef float  f32x4  __attribute__((ext_vector_type(4)));
typedef unsigned short u16x4 __attribute__((ext_vector_type(4)));

__device__ __forceinline__ unsigned short f2bf(float f) {
  unsigned u = __builtin_bit_cast(unsigned, f);
  u += 0x7fffu + ((u >> 16) & 1u);
  return (unsigned short)(u >> 16);
}
__device__ __forceinline__ float bf2f(unsigned short h) {
  unsigned u = ((unsigned)h) << 16;
  return __builtin_bit_cast(float, u);
}

__device__ __forceinline__ void gload16(const void* g, void* l) {
  __builtin_amdgcn_global_load_lds(
      (__attribute__((address_space(1))) void*)const_cast<void*>(g),
      (__attribute__((address_space(3))) void*)l, 16, 0, 0);
}

// ================= phase 1 mega-kernel =================
// blocks [0,1024)            : 3-NN search (VALU-bound long pole)
// blocks [1024,5120)         : transpose points1 -> X0 cols 0..255 (bf16)
// blocks [5120,6144)         : transpose points2 -> p2t f32
// blocks [6144,6784)         : weight casts f32->bf16
// Memory-bound blocks co-schedule with resident NN blocks (MFMA/VALU vs VMEM
// pipes overlap, m114), hiding ~25 us of transpose traffic under NN.

#define NB_NN   1024
#define NB_TP1  4096
#define NB_TP2  1024
#define NB_CAST 640

__device__ __forceinline__ void ins_lex(float d, int i,
                                        float& d0, int& i0,
                                        float& d1, int& i1,
                                        float& d2, int& i2) {
  bool c2 = (d < d2) || (d == d2 && i < i2);
  if (c2) {
    bool c1 = (d < d1) || (d == d1 && i < i1);
    if (c1) {
      d2 = d1; i2 = i1;
      bool c0 = (d < d0) || (d == d0 && i < i0);
      if (c0) { d1 = d0; i1 = i0; d0 = d; i0 = i; }
      else    { d1 = d;  i1 = i; }
    } else    { d2 = d;  i2 = i; }
  }
}

__global__ __launch_bounds__(256) void phase1_kernel(
    const float* __restrict__ xyz1, const float* __restrict__ xyz2,
    const float* __restrict__ points1, const float* __restrict__ points2,
    const float* __restrict__ w0, const float* __restrict__ w1,
    const float* __restrict__ w2,
    int4* __restrict__ idx_out, float4* __restrict__ w_out,
    unsigned short* __restrict__ X0, float* __restrict__ p2t,
    unsigned short* __restrict__ wb0, unsigned short* __restrict__ wb1,
    unsigned short* __restrict__ wb2) {
  __shared__ __align__(16) char smem[33024];
  const int bid = blockIdx.x;
  const int t = threadIdx.x;

  if (bid < NB_NN) {
    // ---- 3-NN: 4 lanes/point, bit-identical distance association ----
#pragma clang fp contract(off)
    f32x4* q = (f32x4*)smem;  // [S_] x,y,z,|q|^2
    int b = bid >> 7;
    int bx = bid & 127;
    const float* x2 = xyz2 + (size_t)b * 3 * S_;
    for (int i = t; i < S_; i += 256) {
      float a = x2[i], c = x2[S_ + i], d = x2[2 * S_ + i];
      q[i] = f32x4{a, c, d, (a * a + c * c) + d * d};
    }
    __syncthreads();

    const int j = t & 3;
    const int pt = bx * 64 + (t >> 2);
    const float* x1 = xyz1 + (size_t)b * 3 * N_;
    float px = x1[pt], py = x1[N_ + pt], pz = x1[2 * N_ + pt];
    float n1 = (px * px + py * py) + pz * pz;

    float d0 = 3.4e38f, d1 = 3.4e38f, d2 = 3.4e38f;
    int i0 = -1, i1 = -1, i2 = -1;
    const int sbase = j * 512;

    for (int s = 0; s < 512; s += 2) {
      int sa = (s + j) & 511;
      int sb = (s + 1 + j) & 511;
      f32x4 qa = q[sbase + sa];
      f32x4 qb = q[sbase + sb];
      float dota = (px * qa.x + py * qa.y) + pz * qa.z;
      float da = (-2.0f * dota + n1) + qa.w;
      float dotb = (px * qb.x + py * qb.y) + pz * qb.z;
      float db = (-2.0f * dotb + n1) + qb.w;
      if (da < d2) {
        int ia = sbase + sa;
        if (da < d1) {
          d2 = d1; i2 = i1;
          if (da < d0) { d1 = d0; i1 = i0; d0 = da; i0 = ia; }
          else         { d1 = da; i1 = ia; }
        } else         { d2 = da; i2 = ia; }
      }
      if (db < d2) {
        int ib_ = sbase + sb;
        if (db < d1) {
          d2 = d1; i2 = i1;
          if (db < d0) { d1 = d0; i1 = i0; d0 = db; i0 = ib_; }
          else         { d1 = db; i1 = ib_; }
        } else         { d2 = db; i2 = ib_; }
      }
    }

#pragma unroll
    for (int m = 1; m <= 2; m <<= 1) {
      float e0 = __shfl_xor(d0, m), e1 = __shfl_xor(d1, m), e2 = __shfl_xor(d2, m);
      int f0 = __shfl_xor(i0, m), f1 = __shfl_xor(i1, m), f2 = __shfl_xor(i2, m);
      ins_lex(e0, f0, d0, i0, d1, i1, d2, i2);
      ins_lex(e1, f1, d0, i0, d1, i1, d2, i2);
      ins_lex(e2, f2, d0, i0, d1, i1, d2, i2);
    }

    if (j == 0) {
      float r0 = 1.0f / (d0 + 1e-8f), r1 = 1.0f / (d1 + 1e-8f), r2 = 1.0f / (d2 + 1e-8f);
      float rs = r0 + r1 + r2;
      int p = b * N_ + pt;
      idx_out[p] = make_int4(i0, i1, i2, 0);
      w_out[p] = make_float4(r0 / rs, r1 / rs, r2 / rs, 0.f);
    }
  } else if (bid < NB_NN + NB_TP1) {
    // ---- points1 [B][256][8192] f32 -> X0 [B][8192][512] bf16 (cols 0..255), 64x64 tiles
    float (*tile)[65] = (float(*)[65])smem;
    int local = bid - NB_NN;
    int b = local >> 9;
    int rem = local & 511;
    int c0 = (rem >> 7) * 64;
    int n0 = (rem & 127) * 64;
    const float* ib = points1 + ((size_t)b * D1_ + c0) * N_ + n0;
    int tx = t & 63, ty4 = t >> 6;
#pragma unroll
    for (int jj = 0; jj < 16; jj++) {
      int row = ty4 + jj * 4;
      tile[row][tx] = ib[(size_t)row * N_ + tx];
    }
    __syncthreads();
    unsigned short* ob = X0 + (size_t)b * N_ * CIN_;
    int tx2 = (t & 31) * 2, ty8 = t >> 5;
#pragma unroll
    for (int jj = 0; jj < 8; jj++) {
      int row = ty8 + jj * 8;  // n offset
      unsigned v = (unsigned)f2bf(tile[tx2][row]) |
                   ((unsigned)f2bf(tile[tx2 + 1][row]) << 16);
      *(unsigned*)(ob + (size_t)(n0 + row) * CIN_ + c0 + tx2) = v;
    }
  } else if (bid < NB_NN + NB_TP1 + NB_TP2) {
    // ---- points2 [B][256][2048] f32 -> p2t [B][2048][256] f32, 64x64 tiles
    float (*tile)[65] = (float(*)[65])smem;
    int local = bid - (NB_NN + NB_TP1);
    int b = local >> 7;
    int rem = local & 127;
    int c0 = (rem >> 5) * 64;
    int s0 = (rem & 31) * 64;
    const float* ib = points2 + ((size_t)b * D2_ + c0) * S_ + s0;
    int tx = t & 63, ty4 = t >> 6;
#pragma unroll
    for (int jj = 0; jj < 16; jj++) {
      int row = ty4 + jj * 4;
      tile[row][tx] = ib[(size_t)row * S_ + tx];
    }
    __syncthreads();
    float* ob = p2t + (size_t)b * S_ * D2_;
#pragma unroll
    for (int jj = 0; jj < 16; jj++) {
      int row = ty4 + jj * 4;  // s offset
      ob[(size_t)(s0 + row) * D2_ + c0 + tx] = tile[tx][row];
    }
  } else {
    // ---- weight casts: 1024 elems/block over concat [w0|w1|w2]
    int local = bid - (NB_NN + NB_TP1 + NB_TP2);
    const float* src;
    unsigned short* dst;
    int off;
    if (local < 256)      { src = w0; dst = wb0; off = local * 1024; }
    else if (local < 512) { src = w1; dst = wb1; off = (local - 256) * 1024; }
    else                  { src = w2; dst = wb2; off = (local - 512) * 1024; }
    int base = off + t * 4;
    float4 v = *(const float4*)(src + base);
    u16x4 o;
    o.x = f2bf(v.x); o.y = f2bf(v.y); o.z = f2bf(v.z); o.w = f2bf(v.w);
    *(u16x4*)(dst + base) = o;
  }
}

// ================= weighted interp -> X0 cols 256..511 =================

__global__ __launch_bounds__(256) void interp_kernel(
    const float* __restrict__ p2t, const int4* __restrict__ idx_in,
    const float4* __restrict__ w_in, unsigned short* __restrict__ X0) {
  int wave = threadIdx.x >> 6, lane = threadIdx.x & 63;
  int p = blockIdx.x * 4 + wave;
  int b = p >> 13;
  int4 id = idx_in[p];
  float4 wt = w_in[p];
  const f32x4* r0 = (const f32x4*)(p2t + ((size_t)b * S_ + id.x) * D2_);
  const f32x4* r1 = (const f32x4*)(p2t + ((size_t)b * S_ + id.y) * D2_);
  const f32x4* r2 = (const f32x4*)(p2t + ((size_t)b * S_ + id.z) * D2_);
  f32x4 a0 = r0[lane], a1 = r1[lane], a2 = r2[lane];
  f32x4 v = wt.x * a0 + wt.y * a1 + wt.z * a2;
  u16x4 o;
  o.x = f2bf(v.x); o.y = f2bf(v.y); o.z = f2bf(v.z); o.w = f2bf(v.w);
  *(u16x4*)(X0 + (size_t)p * CIN_ + D2_ + lane * 4) = o;
}

// ================= bf16 MFMA GEMM (m97 structure) + fused BN stats =========
// A = W [O][512] bf16; B = X [b][8192][512] bf16 (row = point)
// EPI 0: write Y bf16 [b][n][O];  EPI 1: write f32 [b][O][8192]
// Epilogue also accumulates per-channel sum/sumsq (over n) into sums[0..O) and
// sums[512..512+O) via shfl-reduce + atomicAdd (stats on f32 acc, pre-round).

template <int O, int EPI>
__global__ __launch_bounds__(256) void gemm_kernel(
    const unsigned short* __restrict__ Wb, const unsigned short* __restrict__ X,
    void* __restrict__ Yout, float* __restrict__ sums) {
  __shared__ unsigned short As[128 * 32];
  __shared__ unsigned short Bs[128 * 32];
  const int tid = threadIdx.x;
  const int wave = tid >> 6, lane = tid & 63;
  const int wm = wave >> 1, wn = wave & 1;
  const int quad = lane >> 4, l16 = lane & 15;
  const int M0 = blockIdx.y * 128;
  const int N0 = blockIdx.x * 128;
  const unsigned short* Xb = X + (size_t)blockIdx.z * N_ * CIN_;

  const int arow = tid >> 2;
  const int acolb = (tid & 3) * 16;
  const char* Ag = (const char*)Wb + (size_t)(M0 + arow) * (CIN_ * 2) + acolb;
  const char* Bg = (const char*)Xb + (size_t)(N0 + arow) * (CIN_ * 2) + acolb;
  char* AsW0 = (char*)As + wave * 1024;
  char* AsW1 = (char*)As + 4096 + wave * 1024;
  char* BsW0 = (char*)Bs + wave * 1024;
  char* BsW1 = (char*)Bs + 4096 + wave * 1024;
  const int rstep = 64 * (CIN_ * 2);

  f32x4 acc[4][4];
#pragma unroll
  for (int i = 0; i < 4; i++)
#pragma unroll
    for (int j = 0; j < 4; j++) acc[i][j] = f32x4{0.f, 0.f, 0.f, 0.f};

  for (int k0 = 0; k0 < CIN_; k0 += 32) {
    gload16(Ag + (size_t)k0 * 2, AsW0);
    gload16(Ag + rstep + (size_t)k0 * 2, AsW1);
    gload16(Bg + (size_t)k0 * 2, BsW0);
    gload16(Bg + rstep + (size_t)k0 * 2, BsW1);
    __syncthreads();
    bf16x8 af[4], bfr[4];
#pragma unroll
    for (int mt = 0; mt < 4; mt++)
      af[mt] = *(const bf16x8*)(As + (wm * 64 + mt * 16 + l16) * 32 + quad * 8);
#pragma unroll
    for (int nt = 0; nt < 4; nt++)
      bfr[nt] = *(const bf16x8*)(Bs + (wn * 64 + nt * 16 + l16) * 32 + quad * 8);
#pragma unroll
    for (int mt = 0; mt < 4; mt++)
#pragma unroll
      for (int nt = 0; nt < 4; nt++)
        acc[mt][nt] = __builtin_amdgcn_mfma_f32_16x16x32_bf16(af[mt], bfr[nt], acc[mt][nt], 0, 0, 0);
    __syncthreads();
  }

  // ---- fused BN partial stats ----
  {
    float ps[16], pq[16];
#pragma unroll
    for (int mt = 0; mt < 4; mt++)
#pragma unroll
      for (int rr = 0; rr < 4; rr++) {
        float s = 0.f, q = 0.f;
#pragma unroll
        for (int nt = 0; nt < 4; nt++) {
          float v = acc[mt][nt][rr];
          s += v; q += v * v;
        }
        ps[mt * 4 + rr] = s; pq[mt * 4 + rr] = q;
      }
#pragma unroll
    for (int m = 1; m <= 8; m <<= 1) {
#pragma unroll
      for (int i = 0; i < 16; i++) {
        ps[i] += __shfl_xor(ps[i], m);
        pq[i] += __shfl_xor(pq[i], m);
      }
    }
    if (l16 == 0) {
#pragma unroll
      for (int mt = 0; mt < 4; mt++)
#pragma unroll
        for (int rr = 0; rr < 4; rr++) {
          int o = M0 + wm * 64 + mt * 16 + quad * 4 + rr;
          atomicAdd(&sums[o], ps[mt * 4 + rr]);
          atomicAdd(&sums[512 + o], pq[mt * 4 + rr]);
        }
    }
  }

  if constexpr (EPI == 0) {
    unsigned short* Y = (unsigned short*)Yout + (size_t)blockIdx.z * N_ * O;
#pragma unroll
    for (int mt = 0; mt < 4; mt++) {
#pragma unroll
      for (int nt = 0; nt < 4; nt++) {
        int o = M0 + wm * 64 + mt * 16 + quad * 4;
        int n = N0 + wn * 64 + nt * 16 + l16;
        u16x4 v;
        v.x = f2bf(acc[mt][nt].x);
        v.y = f2bf(acc[mt][nt].y);
        v.z = f2bf(acc[mt][nt].z);
        v.w = f2bf(acc[mt][nt].w);
        *(u16x4*)(Y + (size_t)n * O + o) = v;
      }
    }
  } else {
    float* Y = (float*)Yout + (size_t)blockIdx.z * (size_t)O * N_;
#pragma unroll
    for (int mt = 0; mt < 4; mt++) {
#pragma unroll
      for (int nt = 0; nt < 4; nt++) {
        int o = M0 + wm * 64 + mt * 16 + quad * 4;
        int n = N0 + wn * 64 + nt * 16 + l16;
#pragma unroll
        for (int r = 0; r < 4; r++)
          Y[(size_t)(o + r) * N_ + n] = acc[mt][nt][r];
      }
    }
  }
}

// ================= normalize + relu (inline finalize) =================

// in-place on bf16 [65536][512]
__global__ __launch_bounds__(256) void norm_bf16_kernel(
    unsigned short* __restrict__ Y, const float* __restrict__ sums,
    const float* __restrict__ g, const float* __restrict__ beta) {
  __shared__ float sc[512], sh[512];
  int t = threadIdx.x;
  const float inv = 1.0f / 65536.0f;
#pragma unroll
  for (int cc = 0; cc < 2; cc++) {
    int c = t + cc * 256;
    float mean = sums[c] * inv;
    float var = sums[512 + c] * inv - mean * mean;
    float rstd = 1.0f / sqrtf(var + 1e-5f);
    float s = g[c] * rstd;
    sc[c] = s;
    sh[c] = beta[c] - mean * s;
  }
  __syncthreads();
  size_t base = ((size_t)blockIdx.x * 256 + t) * 8;
  int o = (int)(base & 511);
  uint4 raw = *(const uint4*)(Y + base);
  unsigned vv[4] = {raw.x, raw.y, raw.z, raw.w};
#pragma unroll
  for (int j = 0; j < 4; j++) {
    int c = o + j * 2;
    float f0 = bf2f((unsigned short)(vv[j] & 0xffff));
    float f1 = bf2f((unsigned short)(vv[j] >> 16));
    f0 = fmaxf(f0 * sc[c] + sh[c], 0.f);
    f1 = fmaxf(f1 * sc[c + 1] + sh[c + 1], 0.f);
    vv[j] = (unsigned)f2bf(f0) | ((unsigned)f2bf(f1) << 16);
  }
  raw.x = vv[0]; raw.y = vv[1]; raw.z = vv[2]; raw.w = vv[3];
  *(uint4*)(Y + base) = raw;
}

// in-place on f32 [8][256][8192] (= d_out)
__global__ __launch_bounds__(256) void norm_out_kernel(
    float* __restrict__ Y2, const float* __restrict__ sums,
    const float* __restrict__ g, const float* __restrict__ beta) {
  int o = blockIdx.y;
  const float inv = 1.0f / 65536.0f;
  float mean = sums[o] * inv;
  float var = sums[512 + o] * inv - mean * mean;
  float rstd = 1.0f / sqrtf(var + 1e-5f);
  float sc = g[o] * rstd;
  float sh = beta[o] - mean * sc;
  size_t base = ((size_t)blockIdx.z * 256 + o) * N_ + (size_t)blockIdx.x * 1024 +
                (size_t)threadIdx.x * 4;
  f32x4 v = *(const f32x4*)(Y2 + base);
  v = v * sc + sh;
  v.x = fmaxf(v.x, 0.f); v.y = fmaxf(v.y, 0.f);
  v.z = fmaxf(v.z, 0.f); v.w = fmaxf(v.w, 0.f);
  *(f32x4*)(Y2 + base) = v;
}

// ================= launch =================

extern "C" void kernel_launch(void* const* d_in, const int* in_sizes, int n_in,
                              void* d_out, int out_size, void* d_ws, size_t ws_size,
                              hipStream_t stream) {
  const float* xyz1 = (const float*)d_in[0];
  const float* xyz2 = (const float*)d_in[1];
  const float* points1 = (const float*)d_in[2];
  const float* points2 = (const float*)d_in[3];
  const float* w0 = (const float*)d_in[4];
  const float* g0 = (const float*)d_in[6];
  const float* be0 = (const float*)d_in[7];
  const float* w1 = (const float*)d_in[8];
  const float* g1 = (const float*)d_in[10];
  const float* be1 = (const float*)d_in[11];
  const float* w2 = (const float*)d_in[12];
  const float* g2 = (const float*)d_in[14];
  const float* be2 = (const float*)d_in[15];

  char* ws = (char*)d_ws;
  unsigned short* bufA = (unsigned short*)ws;                     // 67,108,864 B
  unsigned short* bufB = (unsigned short*)(ws + 67108864);        // 67,108,864 B
  float* p2t          = (float*)(ws + 134217728);                 // 16,777,216 B
  unsigned short* wb0 = (unsigned short*)(ws + 150994944);        // 524,288 B
  unsigned short* wb1 = (unsigned short*)(ws + 151519232);        // 524,288 B
  unsigned short* wb2 = (unsigned short*)(ws + 152043520);        // 262,144 B
  int4* idxb          = (int4*)(ws + 152305664);                  // 1,048,576 B
  float4* wtb         = (float4*)(ws + 153354240);                // 1,048,576 B
  float* sums         = (float*)(ws + 154402816);                 // 12,288 B

  hipMemsetAsync(sums, 0, 12288, stream);

  phase1_kernel<<<NB_NN + NB_TP1 + NB_TP2 + NB_CAST, 256, 0, stream>>>(
      xyz1, xyz2, points1, points2, w0, w1, w2,
      idxb, wtb, bufA, p2t, wb0, wb1, wb2);

  interp_kernel<<<16384, 256, 0, stream>>>(p2t, idxb, wtb, bufA);

  // layer 0
  gemm_kernel<512, 0><<<dim3(64, 4, 8), 256, 0, stream>>>(wb0, bufA, bufB, sums);
  norm_bf16_kernel<<<16384, 256, 0, stream>>>(bufB, sums, g0, be0);

  // layer 1
  gemm_kernel<512, 0><<<dim3(64, 4, 8), 256, 0, stream>>>(wb1, bufB, bufA, sums + 1024);
  norm_bf16_kernel<<<16384, 256, 0, stream>>>(bufA, sums + 1024, g1, be1);

  // layer 2 (f32 epilogue straight into d_out, [b][o][n])
  gemm_kernel<256, 1><<<dim3(64, 2, 8), 256, 0, stream>>>(wb2, bufA, (void*)d_out, sums + 2048);
  norm_out_kernel<<<dim3(8, 256, 8), 256, 0, stream>>>((float*)d_out, sums + 2048, g2, be2);
}

// Round 4
// 484.982 us; speedup vs baseline: 1.3622x; 1.3622x over previous
//
#include <hip/hip_runtime.h>
#include <cstdint>
#include <cstddef>

#define B_   8
#define N_   8192
#define S_   2048
#define D1_  256
#define D2_  256
#define CIN_ 512

typedef __bf16 bf16x8 __attribute__((ext_vector_type(8)));
typedef float  f32x4  __attribute__((ext_vector_type(4)));
typedef unsigned short u16x4 __attribute__((ext_vector_type(4)));

__device__ __forceinline__ unsigned short f2bf(float f) {
  unsigned u = __builtin_bit_cast(unsigned, f);
  u += 0x7fffu + ((u >> 16) & 1u);
  return (unsigned short)(u >> 16);
}
__device__ __forceinline__ float bf2f(unsigned short h) {
  unsigned u = ((unsigned)h) << 16;
  return __builtin_bit_cast(float, u);
}

__device__ __forceinline__ void gload16(const void* g, void* l) {
  __builtin_amdgcn_global_load_lds(
      (__attribute__((address_space(1))) void*)const_cast<void*>(g),
      (__attribute__((address_space(3))) void*)l, 16, 0, 0);
}

// ================= phase 1 mega-kernel =================
// blocks [0,1024)    : 3-NN search (VALU-bound long pole)
// blocks [1024,5120) : transpose points1 -> X0 cols 0..255 (bf16)
// blocks [5120,6144) : transpose points2 -> p2t f32
// blocks [6144,6784) : weight casts f32->bf16

#define NB_NN   1024
#define NB_TP1  4096
#define NB_TP2  1024
#define NB_CAST 640

__device__ __forceinline__ void ins_lex(float d, int i,
                                        float& d0, int& i0,
                                        float& d1, int& i1,
                                        float& d2, int& i2) {
  bool c2 = (d < d2) || (d == d2 && i < i2);
  if (c2) {
    bool c1 = (d < d1) || (d == d1 && i < i1);
    if (c1) {
      d2 = d1; i2 = i1;
      bool c0 = (d < d0) || (d == d0 && i < i0);
      if (c0) { d1 = d0; i1 = i0; d0 = d; i0 = i; }
      else    { d1 = d;  i1 = i; }
    } else    { d2 = d;  i2 = i; }
  }
}

__global__ __launch_bounds__(256) void phase1_kernel(
    const float* __restrict__ xyz1, const float* __restrict__ xyz2,
    const float* __restrict__ points1, const float* __restrict__ points2,
    const float* __restrict__ w0, const float* __restrict__ w1,
    const float* __restrict__ w2,
    int4* __restrict__ idx_out, float4* __restrict__ w_out,
    unsigned short* __restrict__ X0, float* __restrict__ p2t,
    unsigned short* __restrict__ wb0, unsigned short* __restrict__ wb1,
    unsigned short* __restrict__ wb2) {
  __shared__ __align__(16) char smem[33024];
  const int bid = blockIdx.x;
  const int t = threadIdx.x;

  if (bid < NB_NN) {
    // ---- 3-NN: 4 lanes/point, bit-identical distance association ----
#pragma clang fp contract(off)
    f32x4* q = (f32x4*)smem;  // [S_] x,y,z,|q|^2
    int b = bid >> 7;
    int bx = bid & 127;
    const float* x2 = xyz2 + (size_t)b * 3 * S_;
    for (int i = t; i < S_; i += 256) {
      float a = x2[i], c = x2[S_ + i], d = x2[2 * S_ + i];
      q[i] = f32x4{a, c, d, (a * a + c * c) + d * d};
    }
    __syncthreads();

    const int j = t & 3;
    const int pt = bx * 64 + (t >> 2);
    const float* x1 = xyz1 + (size_t)b * 3 * N_;
    float px = x1[pt], py = x1[N_ + pt], pz = x1[2 * N_ + pt];
    float n1 = (px * px + py * py) + pz * pz;

    float d0 = 3.4e38f, d1 = 3.4e38f, d2 = 3.4e38f;
    int i0 = -1, i1 = -1, i2 = -1;
    const int sbase = j * 512;

    for (int s = 0; s < 512; s += 2) {
      int sa = (s + j) & 511;
      int sb = (s + 1 + j) & 511;
      f32x4 qa = q[sbase + sa];
      f32x4 qb = q[sbase + sb];
      float dota = (px * qa.x + py * qa.y) + pz * qa.z;
      float da = (-2.0f * dota + n1) + qa.w;
      float dotb = (px * qb.x + py * qb.y) + pz * qb.z;
      float db = (-2.0f * dotb + n1) + qb.w;
      if (da < d2) {
        int ia = sbase + sa;
        if (da < d1) {
          d2 = d1; i2 = i1;
          if (da < d0) { d1 = d0; i1 = i0; d0 = da; i0 = ia; }
          else         { d1 = da; i1 = ia; }
        } else         { d2 = da; i2 = ia; }
      }
      if (db < d2) {
        int ib_ = sbase + sb;
        if (db < d1) {
          d2 = d1; i2 = i1;
          if (db < d0) { d1 = d0; i1 = i0; d0 = db; i0 = ib_; }
          else         { d1 = db; i1 = ib_; }
        } else         { d2 = db; i2 = ib_; }
      }
    }

#pragma unroll
    for (int m = 1; m <= 2; m <<= 1) {
      float e0 = __shfl_xor(d0, m), e1 = __shfl_xor(d1, m), e2 = __shfl_xor(d2, m);
      int f0 = __shfl_xor(i0, m), f1 = __shfl_xor(i1, m), f2 = __shfl_xor(i2, m);
      ins_lex(e0, f0, d0, i0, d1, i1, d2, i2);
      ins_lex(e1, f1, d0, i0, d1, i1, d2, i2);
      ins_lex(e2, f2, d0, i0, d1, i1, d2, i2);
    }

    if (j == 0) {
      float r0 = 1.0f / (d0 + 1e-8f), r1 = 1.0f / (d1 + 1e-8f), r2 = 1.0f / (d2 + 1e-8f);
      float rs = r0 + r1 + r2;
      int p = b * N_ + pt;
      idx_out[p] = make_int4(i0, i1, i2, 0);
      w_out[p] = make_float4(r0 / rs, r1 / rs, r2 / rs, 0.f);
    }
  } else if (bid < NB_NN + NB_TP1) {
    // ---- points1 [B][256][8192] f32 -> X0 [B][8192][512] bf16 (cols 0..255)
    float (*tile)[65] = (float(*)[65])smem;
    int local = bid - NB_NN;
    int b = local >> 9;
    int rem = local & 511;
    int c0 = (rem >> 7) * 64;
    int n0 = (rem & 127) * 64;
    const float* ib = points1 + ((size_t)b * D1_ + c0) * N_ + n0;
    int tx = t & 63, ty4 = t >> 6;
#pragma unroll
    for (int jj = 0; jj < 16; jj++) {
      int row = ty4 + jj * 4;
      tile[row][tx] = ib[(size_t)row * N_ + tx];
    }
    __syncthreads();
    unsigned short* ob = X0 + (size_t)b * N_ * CIN_;
    int tx2 = (t & 31) * 2, ty8 = t >> 5;
#pragma unroll
    for (int jj = 0; jj < 8; jj++) {
      int row = ty8 + jj * 8;  // n offset
      unsigned v = (unsigned)f2bf(tile[tx2][row]) |
                   ((unsigned)f2bf(tile[tx2 + 1][row]) << 16);
      *(unsigned*)(ob + (size_t)(n0 + row) * CIN_ + c0 + tx2) = v;
    }
  } else if (bid < NB_NN + NB_TP1 + NB_TP2) {
    // ---- points2 [B][256][2048] f32 -> p2t [B][2048][256] f32
    float (*tile)[65] = (float(*)[65])smem;
    int local = bid - (NB_NN + NB_TP1);
    int b = local >> 7;
    int rem = local & 127;
    int c0 = (rem >> 5) * 64;
    int s0 = (rem & 31) * 64;
    const float* ib = points2 + ((size_t)b * D2_ + c0) * S_ + s0;
    int tx = t & 63, ty4 = t >> 6;
#pragma unroll
    for (int jj = 0; jj < 16; jj++) {
      int row = ty4 + jj * 4;
      tile[row][tx] = ib[(size_t)row * S_ + tx];
    }
    __syncthreads();
    float* ob = p2t + (size_t)b * S_ * D2_;
#pragma unroll
    for (int jj = 0; jj < 16; jj++) {
      int row = ty4 + jj * 4;  // s offset
      ob[(size_t)(s0 + row) * D2_ + c0 + tx] = tile[tx][row];
    }
  } else {
    // ---- weight casts
    int local = bid - (NB_NN + NB_TP1 + NB_TP2);
    const float* src;
    unsigned short* dst;
    int off;
    if (local < 256)      { src = w0; dst = wb0; off = local * 1024; }
    else if (local < 512) { src = w1; dst = wb1; off = (local - 256) * 1024; }
    else                  { src = w2; dst = wb2; off = (local - 512) * 1024; }
    int base = off + t * 4;
    float4 v = *(const float4*)(src + base);
    u16x4 o;
    o.x = f2bf(v.x); o.y = f2bf(v.y); o.z = f2bf(v.z); o.w = f2bf(v.w);
    *(u16x4*)(dst + base) = o;
  }
}

// ================= weighted interp -> X0 cols 256..511 =================

__global__ __launch_bounds__(256) void interp_kernel(
    const float* __restrict__ p2t, const int4* __restrict__ idx_in,
    const float4* __restrict__ w_in, unsigned short* __restrict__ X0) {
  int wave = threadIdx.x >> 6, lane = threadIdx.x & 63;
  int p = blockIdx.x * 4 + wave;
  int b = p >> 13;
  int4 id = idx_in[p];
  float4 wt = w_in[p];
  const f32x4* r0 = (const f32x4*)(p2t + ((size_t)b * S_ + id.x) * D2_);
  const f32x4* r1 = (const f32x4*)(p2t + ((size_t)b * S_ + id.y) * D2_);
  const f32x4* r2 = (const f32x4*)(p2t + ((size_t)b * S_ + id.z) * D2_);
  f32x4 a0 = r0[lane], a1 = r1[lane], a2 = r2[lane];
  f32x4 v = wt.x * a0 + wt.y * a1 + wt.z * a2;
  u16x4 o;
  o.x = f2bf(v.x); o.y = f2bf(v.y); o.z = f2bf(v.z); o.w = f2bf(v.w);
  *(u16x4*)(X0 + (size_t)p * CIN_ + D2_ + lane * 4) = o;
}

// ================= bf16 MFMA GEMM (m97 structure, XOR-swizzled LDS) ========
// A = W [O][512] bf16; B = X [b][8192][512] bf16 (row = point)
// LDS slot (row, c) holds global 16B-chunk q=(c - (row>>2))&3 of that row;
// loader permutes per-lane GLOBAL source (LDS dest is HW-fixed base+lane*16),
// reader uses chunk c=(quad + (row>>2))&3. Reduces ds_read_b128 phase
// conflicts 4-way -> 2-way (free per m136). Pure layout permutation.
// EPI 0: write Y bf16 [b][n][O];  EPI 1: write f32 [b][O][8192]

template <int O, int EPI>
__global__ __launch_bounds__(256) void gemm_kernel(
    const unsigned short* __restrict__ Wb, const unsigned short* __restrict__ X,
    void* __restrict__ Yout) {
  __shared__ unsigned short As[128 * 32];
  __shared__ unsigned short Bs[128 * 32];
  const int tid = threadIdx.x;
  const int wave = tid >> 6, lane = tid & 63;
  const int wm = wave >> 1, wn = wave & 1;
  const int quad = lane >> 4, l16 = lane & 15;
  const int M0 = blockIdx.y * 128;
  const int N0 = blockIdx.x * 128;
  const unsigned short* Xb = X + (size_t)blockIdx.z * N_ * CIN_;

  const int arow = tid >> 2;                       // 0..63
  const int qsw = ((tid & 3) - (tid >> 4)) & 3;    // swizzled global chunk
  const char* Ag = (const char*)Wb + (size_t)(M0 + arow) * (CIN_ * 2) + qsw * 16;
  const char* Bg = (const char*)Xb + (size_t)(N0 + arow) * (CIN_ * 2) + qsw * 16;
  char* AsW0 = (char*)As + wave * 1024;
  char* AsW1 = (char*)As + 4096 + wave * 1024;
  char* BsW0 = (char*)Bs + wave * 1024;
  char* BsW1 = (char*)Bs + 4096 + wave * 1024;
  const int rstep = 64 * (CIN_ * 2);
  const int csw = (quad + (l16 >> 2)) & 3;         // swizzled LDS chunk (reader)

  f32x4 acc[4][4];
#pragma unroll
  for (int i = 0; i < 4; i++)
#pragma unroll
    for (int j = 0; j < 4; j++) acc[i][j] = f32x4{0.f, 0.f, 0.f, 0.f};

  for (int k0 = 0; k0 < CIN_; k0 += 32) {
    gload16(Ag + (size_t)k0 * 2, AsW0);
    gload16(Ag + rstep + (size_t)k0 * 2, AsW1);
    gload16(Bg + (size_t)k0 * 2, BsW0);
    gload16(Bg + rstep + (size_t)k0 * 2, BsW1);
    __syncthreads();
    bf16x8 af[4], bfr[4];
#pragma unroll
    for (int mt = 0; mt < 4; mt++)
      af[mt] = *(const bf16x8*)(As + (wm * 64 + mt * 16 + l16) * 32 + csw * 8);
#pragma unroll
    for (int nt = 0; nt < 4; nt++)
      bfr[nt] = *(const bf16x8*)(Bs + (wn * 64 + nt * 16 + l16) * 32 + csw * 8);
#pragma unroll
    for (int mt = 0; mt < 4; mt++)
#pragma unroll
      for (int nt = 0; nt < 4; nt++)
        acc[mt][nt] = __builtin_amdgcn_mfma_f32_16x16x32_bf16(af[mt], bfr[nt], acc[mt][nt], 0, 0, 0);
    __syncthreads();
  }

  if constexpr (EPI == 0) {
    unsigned short* Y = (unsigned short*)Yout + (size_t)blockIdx.z * N_ * O;
#pragma unroll
    for (int mt = 0; mt < 4; mt++) {
#pragma unroll
      for (int nt = 0; nt < 4; nt++) {
        int o = M0 + wm * 64 + mt * 16 + quad * 4;
        int n = N0 + wn * 64 + nt * 16 + l16;
        u16x4 v;
        v.x = f2bf(acc[mt][nt].x);
        v.y = f2bf(acc[mt][nt].y);
        v.z = f2bf(acc[mt][nt].z);
        v.w = f2bf(acc[mt][nt].w);
        *(u16x4*)(Y + (size_t)n * O + o) = v;
      }
    }
  } else {
    float* Y = (float*)Yout + (size_t)blockIdx.z * (size_t)O * N_;
#pragma unroll
    for (int mt = 0; mt < 4; mt++) {
#pragma unroll
      for (int nt = 0; nt < 4; nt++) {
        int o = M0 + wm * 64 + mt * 16 + quad * 4;
        int n = N0 + wn * 64 + nt * 16 + l16;
#pragma unroll
        for (int r = 0; r < 4; r++)
          Y[(size_t)(o + r) * N_ + n] = acc[mt][nt][r];
      }
    }
  }
}

// ================= BN stats (dedicated kernels, round-2 proven) ============

// Y bf16 [65536 rows][512], channel = fast dim
__global__ __launch_bounds__(256) void stats_bf16_kernel(
    const unsigned short* __restrict__ Y, float* __restrict__ sums) {
  int t = threadIdx.x;
  int c = t * 2;
  size_t row0 = (size_t)blockIdx.x * 256;
  float s0 = 0, s1 = 0, q0 = 0, q1 = 0;
  for (int r = 0; r < 256; r++) {
    unsigned v = *(const unsigned*)(Y + (row0 + r) * CIN_ + c);
    float f0 = bf2f((unsigned short)(v & 0xffff));
    float f1 = bf2f((unsigned short)(v >> 16));
    s0 += f0; s1 += f1; q0 += f0 * f0; q1 += f1 * f1;
  }
  atomicAdd(&sums[c], s0);
  atomicAdd(&sums[c + 1], s1);
  atomicAdd(&sums[512 + c], q0);
  atomicAdd(&sums[512 + c + 1], q1);
}

// Y2 f32 [8][256][8192]: per (o,b) row sums
__global__ __launch_bounds__(256) void stats_f32_kernel(
    const float* __restrict__ Y2, float* __restrict__ sums) {
  int o = blockIdx.x, b = blockIdx.y, t = threadIdx.x;
  const float* row = Y2 + ((size_t)b * 256 + o) * N_;
  float s = 0, q = 0;
#pragma unroll
  for (int j = 0; j < 8; j++) {
    f32x4 v = *(const f32x4*)(row + (size_t)(t + j * 256) * 4);
    s += (v.x + v.y) + (v.z + v.w);
    q += (v.x * v.x + v.y * v.y) + (v.z * v.z + v.w * v.w);
  }
  __shared__ float rs[256], rq[256];
  rs[t] = s; rq[t] = q;
  __syncthreads();
  for (int off = 128; off > 0; off >>= 1) {
    if (t < off) { rs[t] += rs[t + off]; rq[t] += rq[t + off]; }
    __syncthreads();
  }
  if (t == 0) {
    atomicAdd(&sums[o], rs[0]);
    atomicAdd(&sums[512 + o], rq[0]);
  }
}

// ================= normalize + relu (inline finalize) =================

// in-place on bf16 [65536][512]
__global__ __launch_bounds__(256) void norm_bf16_kernel(
    unsigned short* __restrict__ Y, const float* __restrict__ sums,
    const float* __restrict__ g, const float* __restrict__ beta) {
  __shared__ float sc[512], sh[512];
  int t = threadIdx.x;
  const float inv = 1.0f / 65536.0f;
#pragma unroll
  for (int cc = 0; cc < 2; cc++) {
    int c = t + cc * 256;
    float mean = sums[c] * inv;
    float var = sums[512 + c] * inv - mean * mean;
    float rstd = 1.0f / sqrtf(var + 1e-5f);
    float s = g[c] * rstd;
    sc[c] = s;
    sh[c] = beta[c] - mean * s;
  }
  __syncthreads();
  size_t base = ((size_t)blockIdx.x * 256 + t) * 8;
  int o = (int)(base & 511);
  uint4 raw = *(const uint4*)(Y + base);
  unsigned vv[4] = {raw.x, raw.y, raw.z, raw.w};
#pragma unroll
  for (int j = 0; j < 4; j++) {
    int c = o + j * 2;
    float f0 = bf2f((unsigned short)(vv[j] & 0xffff));
    float f1 = bf2f((unsigned short)(vv[j] >> 16));
    f0 = fmaxf(f0 * sc[c] + sh[c], 0.f);
    f1 = fmaxf(f1 * sc[c + 1] + sh[c + 1], 0.f);
    vv[j] = (unsigned)f2bf(f0) | ((unsigned)f2bf(f1) << 16);
  }
  raw.x = vv[0]; raw.y = vv[1]; raw.z = vv[2]; raw.w = vv[3];
  *(uint4*)(Y + base) = raw;
}

// in-place on f32 [8][256][8192] (= d_out)
__global__ __launch_bounds__(256) void norm_out_kernel(
    float* __restrict__ Y2, const float* __restrict__ sums,
    const float* __restrict__ g, const float* __restrict__ beta) {
  int o = blockIdx.y;
  const float inv = 1.0f / 65536.0f;
  float mean = sums[o] * inv;
  float var = sums[512 + o] * inv - mean * mean;
  float rstd = 1.0f / sqrtf(var + 1e-5f);
  float sc = g[o] * rstd;
  float sh = beta[o] - mean * sc;
  size_t base = ((size_t)blockIdx.z * 256 + o) * N_ + (size_t)blockIdx.x * 1024 +
                (size_t)threadIdx.x * 4;
  f32x4 v = *(const f32x4*)(Y2 + base);
  v = v * sc + sh;
  v.x = fmaxf(v.x, 0.f); v.y = fmaxf(v.y, 0.f);
  v.z = fmaxf(v.z, 0.f); v.w = fmaxf(v.w, 0.f);
  *(f32x4*)(Y2 + base) = v;
}

// ================= launch =================

extern "C" void kernel_launch(void* const* d_in, const int* in_sizes, int n_in,
                              void* d_out, int out_size, void* d_ws, size_t ws_size,
                              hipStream_t stream) {
  const float* xyz1 = (const float*)d_in[0];
  const float* xyz2 = (const float*)d_in[1];
  const float* points1 = (const float*)d_in[2];
  const float* points2 = (const float*)d_in[3];
  const float* w0 = (const float*)d_in[4];
  const float* g0 = (const float*)d_in[6];
  const float* be0 = (const float*)d_in[7];
  const float* w1 = (const float*)d_in[8];
  const float* g1 = (const float*)d_in[10];
  const float* be1 = (const float*)d_in[11];
  const float* w2 = (const float*)d_in[12];
  const float* g2 = (const float*)d_in[14];
  const float* be2 = (const float*)d_in[15];

  char* ws = (char*)d_ws;
  unsigned short* bufA = (unsigned short*)ws;                     // 67,108,864 B
  unsigned short* bufB = (unsigned short*)(ws + 67108864);        // 67,108,864 B
  float* p2t          = (float*)(ws + 134217728);                 // 16,777,216 B
  unsigned short* wb0 = (unsigned short*)(ws + 150994944);        // 524,288 B
  unsigned short* wb1 = (unsigned short*)(ws + 151519232);        // 524,288 B
  unsigned short* wb2 = (unsigned short*)(ws + 152043520);        // 262,144 B
  int4* idxb          = (int4*)(ws + 152305664);                  // 1,048,576 B
  float4* wtb         = (float4*)(ws + 153354240);                // 1,048,576 B
  float* sums         = (float*)(ws + 154402816);                 // 12,288 B

  hipMemsetAsync(sums, 0, 12288, stream);

  phase1_kernel<<<NB_NN + NB_TP1 + NB_TP2 + NB_CAST, 256, 0, stream>>>(
      xyz1, xyz2, points1, points2, w0, w1, w2,
      idxb, wtb, bufA, p2t, wb0, wb1, wb2);

  interp_kernel<<<16384, 256, 0, stream>>>(p2t, idxb, wtb, bufA);

  // layer 0
  gemm_kernel<512, 0><<<dim3(64, 4, 8), 256, 0, stream>>>(wb0, bufA, bufB);
  stats_bf16_kernel<<<256, 256, 0, stream>>>(bufB, sums);
  norm_bf16_kernel<<<16384, 256, 0, stream>>>(bufB, sums, g0, be0);

  // layer 1
  gemm_kernel<512, 0><<<dim3(64, 4, 8), 256, 0, stream>>>(wb1, bufB, bufA);
  stats_bf16_kernel<<<256, 256, 0, stream>>>(bufA, sums + 1024);
  norm_bf16_kernel<<<16384, 256, 0, stream>>>(bufA, sums + 1024, g1, be1);

  // layer 2 (f32 epilogue straight into d_out, [b][o][n])
  gemm_kernel<256, 1><<<dim3(64, 2, 8), 256, 0, stream>>>(wb2, bufA, (void*)d_out);
  stats_f32_kernel<<<dim3(256, 8), 256, 0, stream>>>((const float*)d_out, sums + 2048);
  norm_out_kernel<<<dim3(8, 256, 8), 256, 0, stream>>>((float*)d_out, sums + 2048, g2, be2);
}